// Round 3
// baseline (3203.830 us; speedup 1.0000x reference)
//
#include <hip/hip_runtime.h>

// LiquidNN LTC: B=512, S=512, D=H=128, O=1, UNFOLDS=6, dt=0.1, tau=1.
// R2 -> R3: wave-synchronous design. One block = ONE wave (64 lanes) = one
// batch row; grid=512 (2 waves/CU). NO __syncthreads anywhere: DS ops are
// in-order per wave, so hbuf write -> read needs no barrier. Each lane owns
// outputs (ln, ln+64) with FULL-K dot products (no cross-lane reduction).
// All weight rows register-resident: 4 sets x 64 v2h = 256 VGPRs (~360 total,
// under the 450 spill point; 1 wave/SIMD is all the grid supplies anyway).
// R2 post-mortem: bottleneck is serial chain latency L per matvec (~1000 cyc),
// dominated by ds_write->barrier->ds_read round trip. This removes the barrier.

typedef _Float16 v2h __attribute__((ext_vector_type(2)));

#define S_LEN 512
#define HDIM 128
#define NUNF 6
#define DTC 0.1f

__device__ __forceinline__ float fast_tanh(float y) {
    // tanh(y) = 1 - 2/(e^{2y}+1); exp+rcp based, NaN-free at +-inf
    float u = __expf(2.0f * y);
    return 1.0f - __fdividef(2.0f, u + 1.0f);
}

__global__ __launch_bounds__(64, 1)
void ltc_kernel(const float* __restrict__ x,
                const float* __restrict__ W_in,
                const float* __restrict__ b_in,
                const float* __restrict__ W_r,
                const float* __restrict__ b_r,
                const float* __restrict__ W_fc,
                const float* __restrict__ b_fc,
                float* __restrict__ out)
{
    const int b  = blockIdx.x;
    const int ln = threadIdx.x;   // 0..63
    const int o0 = ln;            // first owned output
    const int o1 = ln + 64;       // second owned output

    __shared__ __align__(16) _Float16 hbuf[HDIM];
    __shared__ __align__(16) _Float16 xbuf[HDIM];

    // ---- one-time: 4 weight rows into registers, natural K order f16 pairs ----
    v2h wr0[64], wr1[64], wi0[64], wi1[64];   // 256 VGPRs
    {
        const float2* r0 = reinterpret_cast<const float2*>(W_r  + o0 * HDIM);
        const float2* r1 = reinterpret_cast<const float2*>(W_r  + o1 * HDIM);
        const float2* i0 = reinterpret_cast<const float2*>(W_in + o0 * HDIM);
        const float2* i1 = reinterpret_cast<const float2*>(W_in + o1 * HDIM);
#pragma unroll
        for (int p = 0; p < 64; ++p) {
            float2 f;
            f = r0[p]; wr0[p] = v2h{(_Float16)f.x, (_Float16)f.y};
            f = r1[p]; wr1[p] = v2h{(_Float16)f.x, (_Float16)f.y};
            f = i0[p]; wi0[p] = v2h{(_Float16)f.x, (_Float16)f.y};
            f = i1[p]; wi1[p] = v2h{(_Float16)f.x, (_Float16)f.y};
        }
    }
    const float bi0 = b_in[o0], bi1 = b_in[o1];
    const float br0 = b_r[o0],  br1 = b_r[o1];

    const float* x_row = x + (size_t)b * S_LEN * HDIM;

    float h0 = 0.0f, h1 = 0.0f;   // fp32 authoritative h for o0/o1

    // prologue: stage x[b,0,:], zero h LDS copy (wave-sync, no barrier)
    xbuf[o0] = (_Float16)x_row[o0];
    xbuf[o1] = (_Float16)x_row[o1];
    hbuf[o0] = (_Float16)0.0f;
    hbuf[o1] = (_Float16)0.0f;

    for (int s = 0; s < S_LEN; ++s) {
        // prefetch next step's x (vmcnt drained ~3000 cyc later at step end)
        float xn0 = 0.0f, xn1 = 0.0f;
        if (s + 1 < S_LEN) {
            const float* xr = x_row + (size_t)(s + 1) * HDIM;
            xn0 = xr[o0];
            xn1 = xr[o1];
        }

        // ---- input map: xin_o = x[b,s,:].W_in[o,:] + b_in[o]  (full-K dots) ----
        float xin0, xin1;
        {
            const float4* xp = reinterpret_cast<const float4*>(xbuf);
            float4 hv[16];
#pragma unroll
            for (int j = 0; j < 16; ++j) hv[j] = xp[j];
            const v2h* hh = reinterpret_cast<const v2h*>(hv);
            float a0 = 0.f, a1 = 0.f, a2 = 0.f, a3 = 0.f;
            float c0 = 0.f, c1 = 0.f, c2 = 0.f, c3 = 0.f;
#pragma unroll
            for (int p = 0; p < 64; p += 4) {
                a0 = __builtin_amdgcn_fdot2(wi0[p],   hh[p],   a0, false);
                a1 = __builtin_amdgcn_fdot2(wi0[p+1], hh[p+1], a1, false);
                a2 = __builtin_amdgcn_fdot2(wi0[p+2], hh[p+2], a2, false);
                a3 = __builtin_amdgcn_fdot2(wi0[p+3], hh[p+3], a3, false);
                c0 = __builtin_amdgcn_fdot2(wi1[p],   hh[p],   c0, false);
                c1 = __builtin_amdgcn_fdot2(wi1[p+1], hh[p+1], c1, false);
                c2 = __builtin_amdgcn_fdot2(wi1[p+2], hh[p+2], c2, false);
                c3 = __builtin_amdgcn_fdot2(wi1[p+3], hh[p+3], c3, false);
            }
            xin0 = (a0 + a1) + (a2 + a3) + bi0;
            xin1 = (c0 + c1) + (c2 + c3) + bi1;
        }

        // ---- 6 ODE unfolds (wave-synchronous: DS pipe is in-order per wave) ----
#pragma unroll
        for (int u = 0; u < NUNF; ++u) {
            const float4* hp = reinterpret_cast<const float4*>(hbuf);
            float4 hv[16];
#pragma unroll
            for (int j = 0; j < 16; ++j) hv[j] = hp[j];
            const v2h* hh = reinterpret_cast<const v2h*>(hv);
            float a0 = 0.f, a1 = 0.f, a2 = 0.f, a3 = 0.f;
            float c0 = 0.f, c1 = 0.f, c2 = 0.f, c3 = 0.f;
#pragma unroll
            for (int p = 0; p < 64; p += 4) {
                a0 = __builtin_amdgcn_fdot2(wr0[p],   hh[p],   a0, false);
                a1 = __builtin_amdgcn_fdot2(wr0[p+1], hh[p+1], a1, false);
                a2 = __builtin_amdgcn_fdot2(wr0[p+2], hh[p+2], a2, false);
                a3 = __builtin_amdgcn_fdot2(wr0[p+3], hh[p+3], a3, false);
                c0 = __builtin_amdgcn_fdot2(wr1[p],   hh[p],   c0, false);
                c1 = __builtin_amdgcn_fdot2(wr1[p+1], hh[p+1], c1, false);
                c2 = __builtin_amdgcn_fdot2(wr1[p+2], hh[p+2], c2, false);
                c3 = __builtin_amdgcn_fdot2(wr1[p+3], hh[p+3], c3, false);
            }
            float s0 = (a0 + a1) + (a2 + a3);
            float s1 = (c0 + c1) + (c2 + c3);
            float v0 = fast_tanh(xin0 + br0 + s0);
            float v1 = fast_tanh(xin1 + br1 + s1);
            h0 = h0 + DTC * (v0 - h0);   // tau=1: h += dt*(-h+v)
            h1 = h1 + DTC * (v1 - h1);
            hbuf[o0] = (_Float16)h0;
            hbuf[o1] = (_Float16)h1;
        }

        // stage next x (reads of xbuf for step s already retired in-order)
        if (s + 1 < S_LEN) {
            xbuf[o0] = (_Float16)xn0;
            xbuf[o1] = (_Float16)xn1;
        }
    }

    // ---- epilogue: out[b] = h . W_fc[0,:] + b_fc ----
    float partial = h0 * W_fc[o0] + h1 * W_fc[o1];
#pragma unroll
    for (int d = 1; d < 64; d <<= 1) partial += __shfl_xor(partial, d);
    if (ln == 0) out[b] = partial + b_fc[0];
}

extern "C" void kernel_launch(void* const* d_in, const int* in_sizes, int n_in,
                              void* d_out, int out_size, void* d_ws, size_t ws_size,
                              hipStream_t stream) {
    const float* x    = (const float*)d_in[0];
    const float* W_in = (const float*)d_in[1];
    const float* b_in = (const float*)d_in[2];
    const float* W_r  = (const float*)d_in[3];
    const float* b_r  = (const float*)d_in[4];
    const float* W_fc = (const float*)d_in[5];
    const float* b_fc = (const float*)d_in[6];
    float* outp = (float*)d_out;
    (void)in_sizes; (void)n_in; (void)out_size; (void)d_ws; (void)ws_size;
    ltc_kernel<<<dim3(512), dim3(64), 0, stream>>>(x, W_in, b_in, W_r, b_r, W_fc, b_fc, outp);
}

// Round 5
// 1620.193 us; speedup vs baseline: 1.9774x; 1.9774x over previous
//
#include <hip/hip_runtime.h>

// LiquidNN LTC: B=512, S=512, D=H=128, O=1, UNFOLDS=6, dt=0.1, tau=1.
// R5 = R4 with the cvt_pkrtz type-mismatch fixed (bit_cast wrapper).
// Two-phase:
//  Phase 1 (parallel): xin[b,s,o] = x[b,s,:].W_in[o,:] + b_in[o] for all (b,s)
//    -- GEMM, 2048 blocks, LDS-staged x tiles, stored to d_ws as f16 pairs
//    (xin[o], xin[o+64]) packed per lane (67 MB).
//  Phase 2 (serial): 512 single-wave blocks (wave-sync, ZERO barriers), only
//    W_r register-resident (128 VGPRs -- R3's 256-VGPR demand caused demotion).
//    h paired in LDS: slot m = (h[m], h[m+64]) -> one ds_write_b32 per unfold;
//    matvec reads are 16 broadcast ds_read_b128. W_r pre-packed to match.
// Fallback: if ws_size < 67.1 MB, launch the proven R1 kernel (1502 us).

typedef _Float16 v2h __attribute__((ext_vector_type(2)));

#define S_LEN 512
#define HDIM 128
#define BATCH 512
#define NUNF 6
#define DTC 0.1f

__device__ __forceinline__ v2h pk2h(float a, float b) {
    return __builtin_bit_cast(v2h, __builtin_amdgcn_cvt_pkrtz(a, b));
}

__device__ __forceinline__ float fast_tanh(float y) {
    // tanh(y) = 1 - 2/(e^{2y}+1); exp+rcp based, NaN-free at +-inf
    float u = __expf(2.0f * y);
    return 1.0f - __fdividef(2.0f, u + 1.0f);
}

// ---------------- Phase 1: input-map GEMM ----------------
// grid=2048 (128 bs-rows each), block=256 (4 waves; wave w owns rows w*32..+32).
// Lane owns outputs (lane, lane+64); x rows broadcast-read from LDS.
__global__ __launch_bounds__(256, 2)
void xin_kernel(const float* __restrict__ x,
                const float* __restrict__ W_in,
                const float* __restrict__ b_in,
                unsigned int* __restrict__ xin)
{
    __shared__ __align__(16) _Float16 xt[128 * HDIM];   // 32 KB
    const int tid  = threadIdx.x;
    const int w    = tid >> 6;
    const int lane = tid & 63;
    const int bs0  = blockIdx.x * 128;

    // stage 128x128 f32 -> f16 (coalesced float4)
    const float4* xg = reinterpret_cast<const float4*>(x + (size_t)bs0 * HDIM);
#pragma unroll
    for (int i = 0; i < 16; ++i) {
        int idx = i * 1024 + tid * 4;
        float4 v = xg[idx >> 2];
        v2h* d = reinterpret_cast<v2h*>(xt + idx);
        d[0] = pk2h(v.x, v.y);
        d[1] = pk2h(v.z, v.w);
    }

    // W_in rows for (lane, lane+64), natural consecutive pairing
    v2h wi0[64], wi1[64];
    {
        const float4* r0 = reinterpret_cast<const float4*>(W_in + (size_t)lane * HDIM);
        const float4* r1 = reinterpret_cast<const float4*>(W_in + (size_t)(lane + 64) * HDIM);
#pragma unroll
        for (int j = 0; j < 32; ++j) {
            float4 f = r0[j];
            wi0[2*j]   = pk2h(f.x, f.y);
            wi0[2*j+1] = pk2h(f.z, f.w);
            float4 g = r1[j];
            wi1[2*j]   = pk2h(g.x, g.y);
            wi1[2*j+1] = pk2h(g.z, g.w);
        }
    }
    const float bi0 = b_in[lane], bi1 = b_in[lane + 64];
    __syncthreads();

    for (int rr = 0; rr < 32; ++rr) {
        const int r = w * 32 + rr;
        const float4* hp = reinterpret_cast<const float4*>(xt + r * HDIM);
        float a0 = 0.f, a1 = 0.f, c0 = 0.f, c1 = 0.f;
#pragma unroll
        for (int j = 0; j < 16; ++j) {
            float4 q = hp[j];
            const v2h* hh = reinterpret_cast<const v2h*>(&q);
            a0 = __builtin_amdgcn_fdot2(wi0[4*j+0], hh[0], a0, false);
            a1 = __builtin_amdgcn_fdot2(wi0[4*j+1], hh[1], a1, false);
            a0 = __builtin_amdgcn_fdot2(wi0[4*j+2], hh[2], a0, false);
            a1 = __builtin_amdgcn_fdot2(wi0[4*j+3], hh[3], a1, false);
            c0 = __builtin_amdgcn_fdot2(wi1[4*j+0], hh[0], c0, false);
            c1 = __builtin_amdgcn_fdot2(wi1[4*j+1], hh[1], c1, false);
            c0 = __builtin_amdgcn_fdot2(wi1[4*j+2], hh[2], c0, false);
            c1 = __builtin_amdgcn_fdot2(wi1[4*j+3], hh[3], c1, false);
        }
        v2h pk = pk2h(a0 + a1 + bi0, c0 + c1 + bi1);
        xin[(size_t)(bs0 + r) * 64 + lane] = __builtin_bit_cast(unsigned int, pk);
    }
}

// ---------------- Phase 2: serial recurrence, wave-synchronous ----------------
__global__ __launch_bounds__(64, 1)
void ltc_kernel(const unsigned int* __restrict__ xin,
                const float* __restrict__ W_r,
                const float* __restrict__ b_r,
                const float* __restrict__ W_fc,
                const float* __restrict__ b_fc,
                float* __restrict__ out)
{
    const int b  = blockIdx.x;
    const int ln = threadIdx.x;        // 0..63
    const int o0 = ln, o1 = ln + 64;

    __shared__ __align__(16) v2h hbuf[64];   // slot m = (h[m], h[m+64])

    // W_r rows packed to match paired h layout: wr0[p] = (Wr[o0][p], Wr[o0][p+64])
    v2h wr0[64], wr1[64];   // 128 VGPRs
    {
        const float4* lo0 = reinterpret_cast<const float4*>(W_r + (size_t)o0 * HDIM);
        const float4* hi0 = reinterpret_cast<const float4*>(W_r + (size_t)o0 * HDIM + 64);
        const float4* lo1 = reinterpret_cast<const float4*>(W_r + (size_t)o1 * HDIM);
        const float4* hi1 = reinterpret_cast<const float4*>(W_r + (size_t)o1 * HDIM + 64);
#pragma unroll
        for (int j = 0; j < 16; ++j) {
            float4 a = lo0[j], h = hi0[j];
            wr0[4*j+0] = pk2h(a.x, h.x);
            wr0[4*j+1] = pk2h(a.y, h.y);
            wr0[4*j+2] = pk2h(a.z, h.z);
            wr0[4*j+3] = pk2h(a.w, h.w);
            float4 c = lo1[j], d = hi1[j];
            wr1[4*j+0] = pk2h(c.x, d.x);
            wr1[4*j+1] = pk2h(c.y, d.y);
            wr1[4*j+2] = pk2h(c.z, d.z);
            wr1[4*j+3] = pk2h(c.w, d.w);
        }
    }
    const float br0 = b_r[o0], br1 = b_r[o1];
    const unsigned int* xrow = xin + (size_t)b * S_LEN * 64;

    float h0 = 0.f, h1 = 0.f;
    hbuf[ln] = v2h{(_Float16)0.f, (_Float16)0.f};   // wave-sync: in-order DS pipe
    unsigned int xcur = xrow[ln];                   // s = 0

    for (int s = 0; s < S_LEN; ++s) {
        unsigned int xnext = 0;
        if (s + 1 < S_LEN) xnext = xrow[(s + 1) * 64 + ln];  // prefetch, latency hidden
        v2h xp = __builtin_bit_cast(v2h, xcur);
        const float xs0 = (float)xp.x + br0;   // xin already includes b_in
        const float xs1 = (float)xp.y + br1;

#pragma unroll
        for (int u = 0; u < NUNF; ++u) {
            const float4* hp = reinterpret_cast<const float4*>(hbuf);
            float a0 = 0.f, a1 = 0.f, c0 = 0.f, c1 = 0.f;
#pragma unroll
            for (int j = 0; j < 16; ++j) {
                float4 q = hp[j];               // broadcast ds_read_b128
                const v2h* hh = reinterpret_cast<const v2h*>(&q);
                a0 = __builtin_amdgcn_fdot2(wr0[4*j+0], hh[0], a0, false);
                a1 = __builtin_amdgcn_fdot2(wr0[4*j+1], hh[1], a1, false);
                a0 = __builtin_amdgcn_fdot2(wr0[4*j+2], hh[2], a0, false);
                a1 = __builtin_amdgcn_fdot2(wr0[4*j+3], hh[3], a1, false);
                c0 = __builtin_amdgcn_fdot2(wr1[4*j+0], hh[0], c0, false);
                c1 = __builtin_amdgcn_fdot2(wr1[4*j+1], hh[1], c1, false);
                c0 = __builtin_amdgcn_fdot2(wr1[4*j+2], hh[2], c0, false);
                c1 = __builtin_amdgcn_fdot2(wr1[4*j+3], hh[3], c1, false);
            }
            float v0 = fast_tanh(xs0 + a0 + a1);
            float v1 = fast_tanh(xs1 + c0 + c1);
            h0 = h0 + DTC * (v0 - h0);          // tau=1: h += dt*(-h+v)
            h1 = h1 + DTC * (v1 - h1);
            hbuf[ln] = pk2h(h0, h1);            // one ds_write_b32
        }
        xcur = xnext;
    }

    float partial = h0 * W_fc[o0] + h1 * W_fc[o1];
#pragma unroll
    for (int d = 1; d < 64; d <<= 1) partial += __shfl_xor(partial, d);
    if (ln == 0) out[b] = partial + b_fc[0];
}

// ---------------- Fallback (R1 kernel, known-good 1502 us) ----------------
__global__ __launch_bounds__(256, 2)
void ltc_fallback(const float* __restrict__ x,
                  const float* __restrict__ W_in,
                  const float* __restrict__ b_in,
                  const float* __restrict__ W_r,
                  const float* __restrict__ b_r,
                  const float* __restrict__ W_fc,
                  const float* __restrict__ b_fc,
                  float* __restrict__ out)
{
    const int b     = blockIdx.x;
    const int tid   = threadIdx.x;
    const int o     = tid >> 1;
    const int kh    = tid & 1;
    const int kbase = kh * 64;

    __shared__ __align__(16) _Float16 hbuf[2][HDIM];
    __shared__ __align__(16) _Float16 xbuf[2][HDIM];
    __shared__ float red[4];

    v2h wr[32], wi[32];
    {
        const float4* wrp = reinterpret_cast<const float4*>(W_r  + o * HDIM + kbase);
        const float4* wip = reinterpret_cast<const float4*>(W_in + o * HDIM + kbase);
#pragma unroll
        for (int j = 0; j < 16; ++j) {
            float4 f = wrp[j];
            wr[2*j]   = pk2h(f.x, f.y);
            wr[2*j+1] = pk2h(f.z, f.w);
            float4 g = wip[j];
            wi[2*j]   = pk2h(g.x, g.y);
            wi[2*j+1] = pk2h(g.z, g.w);
        }
    }
    const float binv = b_in[o];
    const float brv  = b_r[o];
    const float* x_row = x + (size_t)b * S_LEN * HDIM;
    float h_o = 0.0f;

    if (tid < HDIM) {
        xbuf[0][tid] = (_Float16)x_row[tid];
        hbuf[0][tid] = (_Float16)0.0f;
    }
    __syncthreads();

    for (int s = 0; s < S_LEN; ++s) {
        float xnext = 0.0f;
        if (tid < HDIM && s + 1 < S_LEN)
            xnext = x_row[(size_t)(s + 1) * HDIM + tid];

        float xin_o;
        {
            const float4* hp = reinterpret_cast<const float4*>(&xbuf[s & 1][kbase]);
            float4 hv[8];
#pragma unroll
            for (int j = 0; j < 8; ++j) hv[j] = hp[j];
            const v2h* hh = reinterpret_cast<const v2h*>(hv);
            float a0 = 0.f, a1 = 0.f, a2 = 0.f, a3 = 0.f;
#pragma unroll
            for (int j = 0; j < 32; j += 4) {
                a0 = __builtin_amdgcn_fdot2(wi[j],   hh[j],   a0, false);
                a1 = __builtin_amdgcn_fdot2(wi[j+1], hh[j+1], a1, false);
                a2 = __builtin_amdgcn_fdot2(wi[j+2], hh[j+2], a2, false);
                a3 = __builtin_amdgcn_fdot2(wi[j+3], hh[j+3], a3, false);
            }
            float sum = (a0 + a1) + (a2 + a3);
            sum += __shfl_xor(sum, 1);
            xin_o = sum + binv;
        }

#pragma unroll
        for (int u = 0; u < NUNF; ++u) {
            const float4* hp = reinterpret_cast<const float4*>(&hbuf[u & 1][kbase]);
            float4 hv[8];
#pragma unroll
            for (int j = 0; j < 8; ++j) hv[j] = hp[j];
            const v2h* hh = reinterpret_cast<const v2h*>(hv);
            float a0 = 0.f, a1 = 0.f, a2 = 0.f, a3 = 0.f;
#pragma unroll
            for (int j = 0; j < 32; j += 4) {
                a0 = __builtin_amdgcn_fdot2(wr[j],   hh[j],   a0, false);
                a1 = __builtin_amdgcn_fdot2(wr[j+1], hh[j+1], a1, false);
                a2 = __builtin_amdgcn_fdot2(wr[j+2], hh[j+2], a2, false);
                a3 = __builtin_amdgcn_fdot2(wr[j+3], hh[j+3], a3, false);
            }
            float sum = (a0 + a1) + (a2 + a3);
            sum += __shfl_xor(sum, 1);
            float yv = xin_o + brv + sum;
            float v  = fast_tanh(yv);
            h_o = h_o + DTC * (v - h_o);
            if ((tid & 1) == 0)
                hbuf[(u + 1) & 1][o] = (_Float16)h_o;
            if (u == NUNF - 1 && tid < HDIM && s + 1 < S_LEN)
                xbuf[(s + 1) & 1][tid] = (_Float16)xnext;
            __syncthreads();
        }
    }

    float partial = 0.0f;
    if ((tid & 1) == 0) partial = h_o * W_fc[o];
#pragma unroll
    for (int d = 1; d < 64; d <<= 1) partial += __shfl_xor(partial, d);
    if ((tid & 63) == 0) red[tid >> 6] = partial;
    __syncthreads();
    if (tid == 0) out[b] = red[0] + red[1] + red[2] + red[3] + b_fc[0];
}

extern "C" void kernel_launch(void* const* d_in, const int* in_sizes, int n_in,
                              void* d_out, int out_size, void* d_ws, size_t ws_size,
                              hipStream_t stream) {
    const float* x    = (const float*)d_in[0];
    const float* W_in = (const float*)d_in[1];
    const float* b_in = (const float*)d_in[2];
    const float* W_r  = (const float*)d_in[3];
    const float* b_r  = (const float*)d_in[4];
    const float* W_fc = (const float*)d_in[5];
    const float* b_fc = (const float*)d_in[6];
    float* outp = (float*)d_out;
    (void)in_sizes; (void)n_in; (void)out_size;

    const size_t need = (size_t)BATCH * S_LEN * 64 * sizeof(unsigned int); // 67.1 MB
    if (ws_size >= need) {
        unsigned int* xin = (unsigned int*)d_ws;
        xin_kernel<<<dim3(2048), dim3(256), 0, stream>>>(x, W_in, b_in, xin);
        ltc_kernel<<<dim3(512), dim3(64), 0, stream>>>(xin, W_r, b_r, W_fc, b_fc, outp);
    } else {
        ltc_fallback<<<dim3(512), dim3(256), 0, stream>>>(x, W_in, b_in, W_r, b_r, W_fc, b_fc, outp);
    }
}